// Round 7
// baseline (860.899 us; speedup 1.0000x reference)
//
#include <hip/hip_runtime.h>
#include <cstdint>
#include <cstddef>

// Problem constants
#define B_  512
#define T_  256
#define D_  256
#define H_  1024
#define K2  512      // effective K = 2*D: [ m*x | m ]; mu-path folded into cvec/Wb
#define N2  2048     // interleaved outputs: col 2m = z preact, col 2m+1 = h_til preact
#define TC  32       // timesteps per chunk
#define NCHUNK 8     // TC*NCHUNK == T_

// Workspace layout (bytes). ~166 MB.
#define OFF_WB    ((size_t)0)                      // bf16 [8][16][256][32]       2 MB
#define OFF_CVEC  ((size_t)2097152)                // f32  [2048]                 8 KB
#define OFF_H     ((size_t)2105344)                // f32  [B][H]                 2 MB
#define OFF_PQ    ((size_t)4202496)                // f32x2 [NCHUNK][B][H]       32 MB
#define OFF_INP2  ((size_t)37756928)               // bf16 [1024][128][512]     128 MB

typedef short   bf16x8 __attribute__((ext_vector_type(8)));   // 8 bf16 (4 VGPRs)
typedef float   f32x4  __attribute__((ext_vector_type(4)));

__device__ __forceinline__ unsigned short f2bf(float f) {
    unsigned int u = __float_as_uint(f);
    u += 0x7fffu + ((u >> 16) & 1u);   // round-to-nearest-even
    return (unsigned short)(u >> 16);
}
__device__ __forceinline__ void async16(const void* g, void* l) {
    __builtin_amdgcn_global_load_lds(
        (const __attribute__((address_space(1))) void*)g,
        (__attribute__((address_space(3))) void*)l, 16, 0, 0);
}

// ---- Prep: effective weights -> blocked+swizzled bf16 layout (LDS-staged side).
// Logical: row rW (z/h interleaved) x col k; cols [0:D)=W1, [D:2D)=W3-W1*mu.
// Physical: [nt 8][ks 16][row 256][32], k-quad kq stored at qp = kq ^ ((row>>1)&3).
__global__ void build_wb(const float* __restrict__ Wz, const float* __restrict__ Wh,
                         const float* __restrict__ xm, unsigned short* __restrict__ Wb) {
    int id  = blockIdx.x * 256 + threadIdx.x;      // uint4 id; total 2048*64
    int kq  = id & 3;
    int row = (id >> 2) & 255;
    int ks  = (id >> 10) & 15;
    int nt  = id >> 14;
    int rW  = nt * 256 + row;
    int m   = rW >> 1;
    const float* W = (rW & 1) ? (Wh + (size_t)m * 768) : (Wz + (size_t)m * 768);
    int k = ks * 32 + kq * 8;
    unsigned short o[8];
    #pragma unroll
    for (int j = 0; j < 8; j++) {
        float v;
        if (k < D_) v = W[k + j];
        else { int d = k - D_ + j; v = W[2 * D_ + d] - W[d] * xm[d]; }
        o[j] = f2bf(v);
    }
    uint4 pk;
    pk.x = (unsigned)o[0] | ((unsigned)o[1] << 16);
    pk.y = (unsigned)o[2] | ((unsigned)o[3] << 16);
    pk.z = (unsigned)o[4] | ((unsigned)o[5] << 16);
    pk.w = (unsigned)o[6] | ((unsigned)o[7] << 16);
    size_t dst = ((size_t)(nt * 16 + ks) * 256 + row) * 32
               + (size_t)((kq ^ ((row >> 1) & 3)) * 8);
    *(uint4*)(Wb + dst) = pk;
}

// ---- Prep: cvec[r] = bias[r] + (W1[r,:] + W2[r,:]) . mu  (interleaved rows) ----
__global__ void build_cvec(const float* __restrict__ Wz, const float* __restrict__ bz,
                           const float* __restrict__ Wh, const float* __restrict__ bh,
                           const float* __restrict__ xm, float* __restrict__ cvec) {
    int r = blockIdx.x;           // 0..2047
    int m = r >> 1;
    int d = threadIdx.x;          // 0..255
    const float* W = (r & 1) ? (Wh + (size_t)m * 768) : (Wz + (size_t)m * 768);
    float v = (W[d] + W[D_ + d]) * xm[d];
    for (int off = 32; off; off >>= 1) v += __shfl_down(v, off);
    __shared__ float red[4];
    if ((d & 63) == 0) red[d >> 6] = v;
    __syncthreads();
    if (d == 0) {
        float bias = (r & 1) ? bh[m] : bz[m];
        cvec[r] = bias + red[0] + red[1] + red[2] + red[3];
    }
}

// ---- Build A rows -> PLAIN row-major bf16 [p 1024][row 128][k 512].
// (A is consumed by per-wave global_load_dwordx4 fragment reads - no swizzle.)
// Row of panel p: b=(p&127)*4+(row>>5), t=(p>>7)*32+(row&31). Cols: [m*x | m]. ----
__global__ void build_inp2(const float* __restrict__ X, const float* __restrict__ Mm,
                           unsigned short* __restrict__ inp2) {
    int id  = blockIdx.x * 256 + threadIdx.x;      // uint4 id; total 1024*128*64
    int k8  = id & 63;
    int row = (id >> 6) & 127;
    int p   = id >> 13;
    int b   = (p & 127) * 4 + (row >> 5);
    int t   = (p >> 7) * 32 + (row & 31);
    int k   = k8 * 8;
    const size_t rbase = ((size_t)b * T_ + t) * D_;
    unsigned short o[8];
    if (k < D_) {
        const float4* xp = (const float4*)(X  + rbase + k);
        const float4* mp = (const float4*)(Mm + rbase + k);
        float4 x0 = xp[0], x1 = xp[1], m0 = mp[0], m1 = mp[1];
        o[0]=f2bf(m0.x*x0.x); o[1]=f2bf(m0.y*x0.y); o[2]=f2bf(m0.z*x0.z); o[3]=f2bf(m0.w*x0.w);
        o[4]=f2bf(m1.x*x1.x); o[5]=f2bf(m1.y*x1.y); o[6]=f2bf(m1.z*x1.z); o[7]=f2bf(m1.w*x1.w);
    } else {
        const float4* mp = (const float4*)(Mm + rbase + (k - D_));
        float4 m0 = mp[0], m1 = mp[1];
        o[0]=f2bf(m0.x); o[1]=f2bf(m0.y); o[2]=f2bf(m0.z); o[3]=f2bf(m0.w);
        o[4]=f2bf(m1.x); o[5]=f2bf(m1.y); o[6]=f2bf(m1.z); o[7]=f2bf(m1.w);
    }
    uint4 pk;
    pk.x = (unsigned)o[0] | ((unsigned)o[1] << 16);
    pk.y = (unsigned)o[2] | ((unsigned)o[3] << 16);
    pk.z = (unsigned)o[4] | ((unsigned)o[5] << 16);
    pk.w = (unsigned)o[6] | ((unsigned)o[7] << 16);
    *(uint4*)(inp2 + ((size_t)p * 128 + row) * 512 + k) = pk;
}

// ---- Fused GEMM + activation + chunk-local scan.
// Tile 128x256, BK=32, 8 waves (wave-tile 64x64, wm=w>>2, wn=w&3).
// A-fragments: per-wave global_load_dwordx4 DIRECT from the plain A panel
//   (L2-resident: the 8 nt-sharers of a panel are adjacent on one XCD),
//   double-buffered in registers (af[2][4]), 1 K-step ahead.
// B: LDS ring-4 (64 KB) via global_load_lds, 2 steps ahead, counted vmcnt,
//   ONE barrier per K-step. Reuse safety: stage of buffer (ks+2)&3 at iter ks
//   is issued after barrier(ks-1); every wave reaching barrier(ks-1) already
//   consumed that buffer at iter ks-2 (compiler lgkmcnt wait precedes its
//   MFMA, which precedes the barrier in program order).
// vmcnt ledger per iter: 2 B-stages + 4 A-loads -> steady vmcnt(6);
// tail vmcnt(4) (iter 14), vmcnt(0) (iter 15). A-load reg deps are ALSO
// compiler-tracked, so correctness never rests on the hand counts.
// LDS read traffic halved vs r5 (B frags only = 64 FLOP/LDS-byte).
__global__ __launch_bounds__(512, 4) void gemm_scan(
    const unsigned short* __restrict__ A,      // [1024][128][512] plain
    const unsigned short* __restrict__ Wb,     // [8][16][256][32] swizzled
    const float* __restrict__ cvec,            // [2048]
    float2* __restrict__ PQ)                   // [NCHUNK][B][1024]
{
    __shared__ __align__(16) unsigned short sm[32768];   // B ring-4 x 8192 (64 KB)
    const int tid  = threadIdx.x;
    const int lane = tid & 63;
    const int w    = tid >> 6;
    const int blk  = blockIdx.x;
    const int p    = (blk >> 6) * 8 + (blk & 7);   // panel 0..1023
    const int nt   = (blk >> 3) & 7;               // ntile 0..7
    const int c    = p >> 7;
    const int bg0  = (p & 127) * 4;

    const int wm = w >> 2, wn = w & 3;
    const int l15 = lane & 15, q = lane >> 4;

    const unsigned short* bsrc  = Wb + (size_t)nt * 131072 + tid * 8;   // + ks*8192
    const unsigned short* abase = A + (size_t)p * 65536
                                + (size_t)(wm * 64 + l15) * 512 + q * 8; // + i*8192 + ks*32

    // B fragment LDS offsets (ushort units), ring-buffer-relative
    int boff[4];
    #pragma unroll
    for (int j = 0; j < 4; j++) {
        int rt = wn * 64 + j * 16 + l15;
        boff[j] = rt * 32 + ((q ^ ((rt >> 1) & 3)) * 8);
    }

#define STAGEB(rng, ks_)                                                        \
    { async16(bsrc + (ks_) * 8192,        sm + (rng) * 8192 + tid * 8);         \
      async16(bsrc + (ks_) * 8192 + 4096, sm + (rng) * 8192 + 4096 + tid * 8); }
#define LOADA(buf, ks_)                                                         \
    { _Pragma("unroll")                                                         \
      for (int i = 0; i < 4; i++)                                               \
          af[buf][i] = *(const bf16x8*)(abase + i * 8192 + (ks_) * 32); }

    f32x4 acc[4][4] = {};
    bf16x8 af[2][4];

    STAGEB(0, 0);
    STAGEB(1, 1);
    LOADA(0, 0);

    #pragma unroll
    for (int ks = 0; ks < 16; ++ks) {
        if (ks + 2 < 16) STAGEB((ks + 2) & 3, ks + 2);   // B two ahead (ring-4)
        if (ks + 1 < 16) LOADA((ks + 1) & 1, ks + 1);    // A one ahead (regs)
        if (ks < 14)       asm volatile("s_waitcnt vmcnt(6)" ::: "memory");
        else if (ks == 14) asm volatile("s_waitcnt vmcnt(4)" ::: "memory");
        else               asm volatile("s_waitcnt vmcnt(0)" ::: "memory");
        asm volatile("s_barrier" ::: "memory");          // single barrier per iter

        bf16x8 bv[4];
        #pragma unroll
        for (int j = 0; j < 4; j++)
            bv[j] = *(const bf16x8*)&sm[(ks & 3) * 8192 + boff[j]];
        __builtin_amdgcn_s_setprio(1);
        #pragma unroll
        for (int i = 0; i < 4; i++)
            #pragma unroll
            for (int j = 0; j < 4; j++)
                acc[i][j] = __builtin_amdgcn_mfma_f32_16x16x32_bf16(af[ks & 1][i], bv[j], acc[i][j], 0, 0, 0);
        __builtin_amdgcn_s_setprio(0);
    }
#undef STAGEB
#undef LOADA

    // ---- epilogue (registers only): activation + pair exchange + affine scan ----
    const float par = (float)(lane & 1);   // col parity: 0 => z (sigmoid), 1 => h~ (tanh)
    const float sg  = 1.f + par;           // sigmoid: 1/(1+e^-v); tanh: 2/(1+e^-2v)-1
    #pragma unroll
    for (int j = 0; j < 4; ++j) {
        const int ncol = nt * 256 + wn * 64 + j * 16 + l15;
        const float cadd = cvec[ncol];
        #pragma unroll
        for (int bl2 = 0; bl2 < 2; ++bl2) {
            // lane holds rows tc = i2*16 + q*4 + r of batch (bg0 + wm*2 + bl2)
            float PA = 1.f, QA = 0.f, PB = 1.f, QB = 0.f;
            #pragma unroll
            for (int r = 0; r < 4; ++r) {
                {   // i2 = 0: t = q*4 + r
                    float v  = acc[bl2 * 2][j][r] + cadd;
                    float a  = sg * __builtin_amdgcn_rcpf(1.f + __expf(-sg * v)) - par;
                    float ap = __shfl_xor(a, 1);
                    float z  = (lane & 1) ? ap : a;
                    float ht = (lane & 1) ? a : ap;
                    float om = 1.f - z;
                    QA = om * QA + z * ht;
                    PA = om * PA;
                }
                {   // i2 = 1: t = 16 + q*4 + r
                    float v  = acc[bl2 * 2 + 1][j][r] + cadd;
                    float a  = sg * __builtin_amdgcn_rcpf(1.f + __expf(-sg * v)) - par;
                    float ap = __shfl_xor(a, 1);
                    float z  = (lane & 1) ? ap : a;
                    float ht = (lane & 1) ? a : ap;
                    float om = 1.f - z;
                    QB = om * QB + z * ht;
                    PB = om * PB;
                }
            }
            // ordered butterfly over q (lane bits 4,5): lower q = earlier time
            #pragma unroll
            for (int s = 16; s <= 32; s <<= 1) {
                float PAp = __shfl_xor(PA, s), QAp = __shfl_xor(QA, s);
                float PBp = __shfl_xor(PB, s), QBp = __shfl_xor(QB, s);
                const bool late = (lane & s) != 0;
                float Pe = late ? PAp : PA,  Qe = late ? QAp : QA;
                float Pl = late ? PA  : PAp, Ql = late ? QA  : QAp;
                PA = Pl * Pe;  QA = Pl * Qe + Ql;
                Pe = late ? PBp : PB;  Qe = late ? QBp : QB;
                Pl = late ? PB  : PBp; Ql = late ? QB  : QBp;
                PB = Pl * Pe;  QB = Pl * Qe + Ql;
            }
            // total over 32 steps: apply A (t=0..15) then B (t=16..31)
            const float Ptot = PB * PA;
            const float Qtot = PB * QA + QB;
            if ((q == bl2 * 2) && ((lane & 1) == 0)) {
                const int npg = ncol >> 1;                 // original hidden idx
                const int bgl = bg0 + wm * 2 + bl2;
                PQ[((size_t)c * B_ + bgl) * H_ + npg] = make_float2(Ptot, Qtot);
            }
        }
    }
}

// ---- Combine the 8 chunk-affine maps: h = P_c*h + Q_c, c = 0..7 ----
__global__ void combine(const float2* __restrict__ PQ, float* __restrict__ hbuf) {
    int v = blockIdx.x * 256 + threadIdx.x;   // B*H threads
    int b = v >> 10;
    int n = v & 1023;
    float h = 0.f;
    #pragma unroll
    for (int c = 0; c < NCHUNK; c++) {
        float2 pq = PQ[((size_t)c * B_ + b) * H_ + n];
        h = pq.x * h + pq.y;
    }
    hbuf[(size_t)b * H_ + n] = h;
}

// ---- Output head: out[b] = sigmoid(h[b,:] . Wout + bout) ----
__global__ void head(const float* __restrict__ hbuf, const float* __restrict__ Wout,
                     const float* __restrict__ bout, float* __restrict__ out) {
    int b = blockIdx.x;
    float s = 0.f;
    for (int n = threadIdx.x; n < H_; n += 256)
        s += hbuf[(size_t)b * H_ + n] * Wout[n];
    for (int off = 32; off; off >>= 1) s += __shfl_down(s, off);
    __shared__ float red[4];
    if ((threadIdx.x & 63) == 0) red[threadIdx.x >> 6] = s;
    __syncthreads();
    if (threadIdx.x == 0) {
        float t = red[0] + red[1] + red[2] + red[3] + bout[0];
        out[b] = 1.f / (1.f + expf(-t));
    }
}

extern "C" void kernel_launch(void* const* d_in, const int* in_sizes, int n_in,
                              void* d_out, int out_size, void* d_ws, size_t ws_size,
                              hipStream_t stream) {
    const float* X    = (const float*)d_in[0];
    const float* Mm   = (const float*)d_in[1];
    const float* xm   = (const float*)d_in[2];
    // d_in[3]=gamma_x: algebraically irrelevant for binary masks (x_tilde == m*x+(1-m)*mu)
    const float* Wz   = (const float*)d_in[4];
    const float* bz   = (const float*)d_in[5];
    // d_in[6]=Wr, d_in[7]=br: dead code in reference (r_t unused) — skipped
    const float* Wh   = (const float*)d_in[8];
    const float* bh   = (const float*)d_in[9];
    const float* Wout = (const float*)d_in[10];
    const float* bout = (const float*)d_in[11];
    float* out = (float*)d_out;

    char* ws = (char*)d_ws;
    unsigned short* Wb    = (unsigned short*)(ws + OFF_WB);
    float*          cvec  = (float*)(ws + OFF_CVEC);
    float*          hbuf  = (float*)(ws + OFF_H);
    float2*         PQ    = (float2*)(ws + OFF_PQ);
    unsigned short* inp2  = (unsigned short*)(ws + OFF_INP2);

    build_wb  <<<dim3(512),  dim3(256), 0, stream>>>(Wz, Wh, xm, Wb);
    build_cvec<<<dim3(N2),   dim3(256), 0, stream>>>(Wz, bz, Wh, bh, xm, cvec);
    build_inp2<<<dim3(32768), dim3(256), 0, stream>>>(X, Mm, inp2);

    // grid = 1024 panels x 8 ntiles, XCD-grouped (panel sharers adjacent per XCD)
    gemm_scan<<<dim3(8192), dim3(512), 0, stream>>>(inp2, Wb, cvec, PQ);

    combine<<<dim3(B_ * H_ / 256), dim3(256), 0, stream>>>(PQ, hbuf);
    head   <<<dim3(B_),            dim3(256), 0, stream>>>(hbuf, Wout, bout, out);
}

// Round 8
// 687.156 us; speedup vs baseline: 1.2528x; 1.2528x over previous
//
#include <hip/hip_runtime.h>
#include <cstdint>
#include <cstddef>

// Problem constants
#define B_  512
#define T_  256
#define D_  256
#define H_  1024
#define K2  512      // effective K = 2*D: [ m*x | m ]; mu-path folded into cvec/Wb
#define N2  2048     // interleaved outputs: col 2m = z preact, col 2m+1 = h_til preact
#define TC  32       // timesteps per chunk
#define NCHUNK 8     // TC*NCHUNK == T_

// Workspace layout (bytes). ~166 MB.
#define OFF_WB    ((size_t)0)                      // bf16 [8][16][256][32]       2 MB
#define OFF_CVEC  ((size_t)2097152)                // f32  [2048]                 8 KB
#define OFF_H     ((size_t)2105344)                // f32  [B][H]                 2 MB
#define OFF_PQ    ((size_t)4202496)                // f32x2 [NCHUNK][B][H]       32 MB
#define OFF_INP2  ((size_t)37756928)               // bf16 [512][16][256][32]   128 MB

typedef short   bf16x8 __attribute__((ext_vector_type(8)));   // 8 bf16 (4 VGPRs)
typedef float   f32x4  __attribute__((ext_vector_type(4)));

__device__ __forceinline__ unsigned short f2bf(float f) {
    unsigned int u = __float_as_uint(f);
    u += 0x7fffu + ((u >> 16) & 1u);   // round-to-nearest-even
    return (unsigned short)(u >> 16);
}
__device__ __forceinline__ void async16(const void* g, void* l) {
    __builtin_amdgcn_global_load_lds(
        (const __attribute__((address_space(1))) void*)g,
        (__attribute__((address_space(3))) void*)l, 16, 0, 0);
}

// ---- Prep: effective weights -> blocked+swizzled bf16 layout.
// Logical: row rW (z/h interleaved) x col k; cols [0:D)=W1, [D:2D)=W3-W1*mu.
// Physical: [nt 8][ks 16][row 256][32], k-quad kq stored at qp = kq ^ ((row>>1)&3).
__global__ void build_wb(const float* __restrict__ Wz, const float* __restrict__ Wh,
                         const float* __restrict__ xm, unsigned short* __restrict__ Wb) {
    int id  = blockIdx.x * 256 + threadIdx.x;      // uint4 id; total 2048*64
    int kq  = id & 3;
    int row = (id >> 2) & 255;
    int ks  = (id >> 10) & 15;
    int nt  = id >> 14;
    int rW  = nt * 256 + row;
    int m   = rW >> 1;
    const float* W = (rW & 1) ? (Wh + (size_t)m * 768) : (Wz + (size_t)m * 768);
    int k = ks * 32 + kq * 8;
    unsigned short o[8];
    #pragma unroll
    for (int j = 0; j < 8; j++) {
        float v;
        if (k < D_) v = W[k + j];
        else { int d = k - D_ + j; v = W[2 * D_ + d] - W[d] * xm[d]; }
        o[j] = f2bf(v);
    }
    uint4 pk;
    pk.x = (unsigned)o[0] | ((unsigned)o[1] << 16);
    pk.y = (unsigned)o[2] | ((unsigned)o[3] << 16);
    pk.z = (unsigned)o[4] | ((unsigned)o[5] << 16);
    pk.w = (unsigned)o[6] | ((unsigned)o[7] << 16);
    size_t dst = ((size_t)(nt * 16 + ks) * 256 + row) * 32
               + (size_t)((kq ^ ((row >> 1) & 3)) * 8);
    *(uint4*)(Wb + dst) = pk;
}

// ---- Prep: cvec[r] = bias[r] + (W1[r,:] + W2[r,:]) . mu  (interleaved rows) ----
__global__ void build_cvec(const float* __restrict__ Wz, const float* __restrict__ bz,
                           const float* __restrict__ Wh, const float* __restrict__ bh,
                           const float* __restrict__ xm, float* __restrict__ cvec) {
    int r = blockIdx.x;           // 0..2047
    int m = r >> 1;
    int d = threadIdx.x;          // 0..255
    const float* W = (r & 1) ? (Wh + (size_t)m * 768) : (Wz + (size_t)m * 768);
    float v = (W[d] + W[D_ + d]) * xm[d];
    for (int off = 32; off; off >>= 1) v += __shfl_down(v, off);
    __shared__ float red[4];
    if ((d & 63) == 0) red[d >> 6] = v;
    __syncthreads();
    if (d == 0) {
        float bias = (r & 1) ? bh[m] : bz[m];
        cvec[r] = bias + red[0] + red[1] + red[2] + red[3];
    }
}

// ---- Build A rows -> blocked+swizzled bf16 [p 512][ks 16][row 256][32].
// Panel p = 256 rows = 8 batches x 32 timesteps:
// b = (p&63)*8 + (row>>5), t = (p>>6)*32 + (row&31). Cols: [m*x | m]. ----
__global__ void build_inp2(const float* __restrict__ X, const float* __restrict__ Mm,
                           unsigned short* __restrict__ inp2) {
    int id  = blockIdx.x * 256 + threadIdx.x;      // uint4 id; total 512*16*256*4
    int kq  = id & 3;
    int row = (id >> 2) & 255;
    int ks  = (id >> 10) & 15;
    int p   = id >> 14;
    int b   = (p & 63) * 8 + (row >> 5);
    int t   = (p >> 6) * 32 + (row & 31);
    int k   = ks * 32 + kq * 8;
    const size_t rbase = ((size_t)b * T_ + t) * D_;
    unsigned short o[8];
    if (k < D_) {
        const float4* xp = (const float4*)(X  + rbase + k);
        const float4* mp = (const float4*)(Mm + rbase + k);
        float4 x0 = xp[0], x1 = xp[1], m0 = mp[0], m1 = mp[1];
        o[0]=f2bf(m0.x*x0.x); o[1]=f2bf(m0.y*x0.y); o[2]=f2bf(m0.z*x0.z); o[3]=f2bf(m0.w*x0.w);
        o[4]=f2bf(m1.x*x1.x); o[5]=f2bf(m1.y*x1.y); o[6]=f2bf(m1.z*x1.z); o[7]=f2bf(m1.w*x1.w);
    } else {
        const float4* mp = (const float4*)(Mm + rbase + (k - D_));
        float4 m0 = mp[0], m1 = mp[1];
        o[0]=f2bf(m0.x); o[1]=f2bf(m0.y); o[2]=f2bf(m0.z); o[3]=f2bf(m0.w);
        o[4]=f2bf(m1.x); o[5]=f2bf(m1.y); o[6]=f2bf(m1.z); o[7]=f2bf(m1.w);
    }
    uint4 pk;
    pk.x = (unsigned)o[0] | ((unsigned)o[1] << 16);
    pk.y = (unsigned)o[2] | ((unsigned)o[3] << 16);
    pk.z = (unsigned)o[4] | ((unsigned)o[5] << 16);
    pk.w = (unsigned)o[6] | ((unsigned)o[7] << 16);
    size_t dst = ((size_t)(p * 16 + ks) * 256 + row) * 32
               + (size_t)((kq ^ ((row >> 1) & 3)) * 8);
    *(uint4*)(inp2 + dst) = pk;
}

// ---- Fused GEMM + activation + chunk-local scan.
// Tile 256x256, BK=32, 8 waves, wave-tile 128x64 (acc[8][4]): LDS-read per
// MFMA drops 0.5 -> 0.375 KB (the R5 limiter was total LDS traffic).
// LDS: ring-3 x (A 16KB + B 16KB) = 96 KB, 1 block/CU, ONE barrier/iter:
//   { vmcnt(4); s_barrier; STAGE(ks+2); ds_read(ks); setprio1; MFMA; setprio0 }
// Reuse safety: STAGE at iter ks overwrites buf((ks-1)%3); any wave past
// barrier(ks) already issued MFMA(ks-1), which required its ds_read(ks-1)
// data complete -> buffer free. vmcnt: 4 stage-ops/iter, 2-iter lead
// (~3000 cyc >> 900-cyc HBM miss); A-load deps never rest on hand counts.
// Grid XCD-grouped: the 8 nt-sharers of a panel sit at blk stride 8 (same
// blk%8 -> same XCD, adjacent) -> A HBM-streamed ~once, W L2-resident.
__global__ __launch_bounds__(512, 2) void gemm_scan(
    const unsigned short* __restrict__ A,      // [512][16][256][32] swizzled
    const unsigned short* __restrict__ Wb,     // [8][16][256][32] swizzled
    const float* __restrict__ cvec,            // [2048]
    float2* __restrict__ PQ)                   // [NCHUNK][B][1024]
{
    __shared__ __align__(16) unsigned short sm[49152];   // A ring3 x 8192u | B ring3 x 8192u
    unsigned short* smA = sm;             // + ring*8192
    unsigned short* smB = sm + 24576;     // + ring*8192
    const int tid  = threadIdx.x;
    const int lane = tid & 63;
    const int w    = tid >> 6;
    const int blk  = blockIdx.x;                   // 4096 = 512 panels x 8 ntiles
    const int p    = (blk >> 6) * 8 + (blk & 7);   // panel 0..511
    const int nt   = (blk >> 3) & 7;               // ntile 0..7
    const int c    = p >> 6;                       // chunk
    const int bg0  = (p & 63) * 8;                 // first global batch of panel

    const int wm = w >> 2, wn = w & 3;
    const int l15 = lane & 15, q = lane >> 4;

    const unsigned short* asrc = A  + (size_t)p  * 131072 + tid * 8;   // + ks*8192
    const unsigned short* bsrc = Wb + (size_t)nt * 131072 + tid * 8;   // + ks*8192

    // fragment LDS offsets (ushort units), ring-buffer-relative, constant over K
    int aoff[8], boff[4];
    #pragma unroll
    for (int i = 0; i < 8; i++) {
        int row = wm * 128 + i * 16 + l15;
        aoff[i] = row * 32 + ((q ^ ((row >> 1) & 3)) * 8);
    }
    #pragma unroll
    for (int j = 0; j < 4; j++) {
        int rt = wn * 64 + j * 16 + l15;
        boff[j] = rt * 32 + ((q ^ ((rt >> 1) & 3)) * 8);
    }

#define STAGE(rng, ks_)                                                 \
    { const unsigned short* as_ = asrc + (size_t)(ks_) * 8192;          \
      const unsigned short* bs_ = bsrc + (size_t)(ks_) * 8192;          \
      async16(as_,        smA + (rng) * 8192 + tid * 8);                \
      async16(as_ + 4096, smA + (rng) * 8192 + 4096 + tid * 8);         \
      async16(bs_,        smB + (rng) * 8192 + tid * 8);                \
      async16(bs_ + 4096, smB + (rng) * 8192 + 4096 + tid * 8); }

    f32x4 acc[8][4] = {};

    STAGE(0, 0);
    STAGE(1, 1);

    #pragma unroll
    for (int ks = 0; ks < 16; ++ks) {
        const int cur = ks % 3;
        if (ks < 15) asm volatile("s_waitcnt vmcnt(4)" ::: "memory");
        else         asm volatile("s_waitcnt vmcnt(0)" ::: "memory");
        asm volatile("s_barrier" ::: "memory");          // single barrier per iter
        if (ks + 2 < 16) STAGE((ks + 2) % 3, ks + 2);    // after barrier: ring-3 safe

        bf16x8 af[8], bv[4];
        #pragma unroll
        for (int i = 0; i < 8; i++)
            af[i] = *(const bf16x8*)&smA[cur * 8192 + aoff[i]];
        #pragma unroll
        for (int j = 0; j < 4; j++)
            bv[j] = *(const bf16x8*)&smB[cur * 8192 + boff[j]];
        __builtin_amdgcn_s_setprio(1);
        #pragma unroll
        for (int i = 0; i < 8; i++)
            #pragma unroll
            for (int j = 0; j < 4; j++)
                acc[i][j] = __builtin_amdgcn_mfma_f32_16x16x32_bf16(af[i], bv[j], acc[i][j], 0, 0, 0);
        __builtin_amdgcn_s_setprio(0);
    }
#undef STAGE

    // ---- epilogue (registers only): activation + pair exchange + affine scan ----
    // acc[i][j] row = wm*128 + i*16 + q*4 + r -> batch_local = wm*4 + (i>>1),
    // tc = (i&1)*16 + q*4 + r. Same verified pair/butterfly as rounds 4-5.
    const float par = (float)(lane & 1);   // col parity: 0 => z (sigmoid), 1 => h~ (tanh)
    const float sg  = 1.f + par;           // sigmoid: 1/(1+e^-v); tanh: 2/(1+e^-2v)-1
    #pragma unroll
    for (int j = 0; j < 4; ++j) {
        const int ncol = nt * 256 + wn * 64 + j * 16 + l15;
        const float cadd = cvec[ncol];
        #pragma unroll
        for (int ig = 0; ig < 4; ++ig) {
            float PA = 1.f, QA = 0.f, PB = 1.f, QB = 0.f;
            #pragma unroll
            for (int r = 0; r < 4; ++r) {
                {   // i2 = 0: tc = q*4 + r
                    float v  = acc[2 * ig][j][r] + cadd;
                    float a  = sg * __builtin_amdgcn_rcpf(1.f + __expf(-sg * v)) - par;
                    float ap = __shfl_xor(a, 1);
                    float z  = (lane & 1) ? ap : a;
                    float ht = (lane & 1) ? a : ap;
                    float om = 1.f - z;
                    QA = om * QA + z * ht;
                    PA = om * PA;
                }
                {   // i2 = 1: tc = 16 + q*4 + r
                    float v  = acc[2 * ig + 1][j][r] + cadd;
                    float a  = sg * __builtin_amdgcn_rcpf(1.f + __expf(-sg * v)) - par;
                    float ap = __shfl_xor(a, 1);
                    float z  = (lane & 1) ? ap : a;
                    float ht = (lane & 1) ? a : ap;
                    float om = 1.f - z;
                    QB = om * QB + z * ht;
                    PB = om * PB;
                }
            }
            // ordered butterfly over q (lane bits 4,5): lower q = earlier time
            #pragma unroll
            for (int s = 16; s <= 32; s <<= 1) {
                float PAp = __shfl_xor(PA, s), QAp = __shfl_xor(QA, s);
                float PBp = __shfl_xor(PB, s), QBp = __shfl_xor(QB, s);
                const bool late = (lane & s) != 0;
                float Pe = late ? PAp : PA,  Qe = late ? QAp : QA;
                float Pl = late ? PA  : PAp, Ql = late ? QA  : QAp;
                PA = Pl * Pe;  QA = Pl * Qe + Ql;
                Pe = late ? PBp : PB;  Qe = late ? QBp : QB;
                Pl = late ? PB  : PBp; Ql = late ? QB  : QBp;
                PB = Pl * Pe;  QB = Pl * Qe + Ql;
            }
            // total over 32 steps: apply A (t=0..15) then B (t=16..31)
            const float Ptot = PB * PA;
            const float Qtot = PB * QA + QB;
            if ((q == ig) && ((lane & 1) == 0)) {       // all lanes hold the total
                const int npg = ncol >> 1;              // original hidden idx
                const int bgl = bg0 + wm * 4 + ig;
                PQ[((size_t)c * B_ + bgl) * H_ + npg] = make_float2(Ptot, Qtot);
            }
        }
    }
}

// ---- Combine the 8 chunk-affine maps: h = P_c*h + Q_c, c = 0..7 ----
__global__ void combine(const float2* __restrict__ PQ, float* __restrict__ hbuf) {
    int v = blockIdx.x * 256 + threadIdx.x;   // B*H threads
    int b = v >> 10;
    int n = v & 1023;
    float h = 0.f;
    #pragma unroll
    for (int c = 0; c < NCHUNK; c++) {
        float2 pq = PQ[((size_t)c * B_ + b) * H_ + n];
        h = pq.x * h + pq.y;
    }
    hbuf[(size_t)b * H_ + n] = h;
}

// ---- Output head: out[b] = sigmoid(h[b,:] . Wout + bout) ----
__global__ void head(const float* __restrict__ hbuf, const float* __restrict__ Wout,
                     const float* __restrict__ bout, float* __restrict__ out) {
    int b = blockIdx.x;
    float s = 0.f;
    for (int n = threadIdx.x; n < H_; n += 256)
        s += hbuf[(size_t)b * H_ + n] * Wout[n];
    for (int off = 32; off; off >>= 1) s += __shfl_down(s, off);
    __shared__ float red[4];
    if ((threadIdx.x & 63) == 0) red[threadIdx.x >> 6] = s;
    __syncthreads();
    if (threadIdx.x == 0) {
        float t = red[0] + red[1] + red[2] + red[3] + bout[0];
        out[b] = 1.f / (1.f + expf(-t));
    }
}

extern "C" void kernel_launch(void* const* d_in, const int* in_sizes, int n_in,
                              void* d_out, int out_size, void* d_ws, size_t ws_size,
                              hipStream_t stream) {
    const float* X    = (const float*)d_in[0];
    const float* Mm   = (const float*)d_in[1];
    const float* xm   = (const float*)d_in[2];
    // d_in[3]=gamma_x: algebraically irrelevant for binary masks (x_tilde == m*x+(1-m)*mu)
    const float* Wz   = (const float*)d_in[4];
    const float* bz   = (const float*)d_in[5];
    // d_in[6]=Wr, d_in[7]=br: dead code in reference (r_t unused) — skipped
    const float* Wh   = (const float*)d_in[8];
    const float* bh   = (const float*)d_in[9];
    const float* Wout = (const float*)d_in[10];
    const float* bout = (const float*)d_in[11];
    float* out = (float*)d_out;

    char* ws = (char*)d_ws;
    unsigned short* Wb    = (unsigned short*)(ws + OFF_WB);
    float*          cvec  = (float*)(ws + OFF_CVEC);
    float*          hbuf  = (float*)(ws + OFF_H);
    float2*         PQ    = (float2*)(ws + OFF_PQ);
    unsigned short* inp2  = (unsigned short*)(ws + OFF_INP2);

    build_wb  <<<dim3(512),   dim3(256), 0, stream>>>(Wz, Wh, xm, Wb);
    build_cvec<<<dim3(N2),    dim3(256), 0, stream>>>(Wz, bz, Wh, bh, xm, cvec);
    build_inp2<<<dim3(32768), dim3(256), 0, stream>>>(X, Mm, inp2);

    // grid = 512 panels x 8 ntiles, XCD-grouped (panel sharers adjacent per XCD)
    gemm_scan<<<dim3(4096), dim3(512), 0, stream>>>(inp2, Wb, cvec, PQ);

    combine<<<dim3(B_ * H_ / 256), dim3(256), 0, stream>>>(PQ, hbuf);
    head   <<<dim3(B_),            dim3(256), 0, stream>>>(hbuf, Wout, bout, out);
}